// Round 8
// baseline (204.100 us; speedup 1.0000x reference)
//
#include <hip/hip_runtime.h>
#include <stdint.h>

#define NUM_NODES 50000
#define B_ 4096
#define N_ 100

typedef float f32x4 __attribute__((ext_vector_type(4)));

__device__ inline float rlf(float x, int i) {
    return __int_as_float(__builtin_amdgcn_readlane(__float_as_int(x), i));
}

// wave64 sum-reduce on the VALU pipe (DPP), result broadcast to all lanes.
template <int CTRL>
__device__ inline float dpp_add(float x) {
    int t = __builtin_amdgcn_update_dpp(0, __float_as_int(x), CTRL, 0xf, 0xf, true);
    return x + __int_as_float(t);
}
__device__ inline float wave_sum64(float x) {
    x = dpp_add<0x111>(x);   // row_shr:1
    x = dpp_add<0x112>(x);   // row_shr:2
    x = dpp_add<0x114>(x);   // row_shr:4
    x = dpp_add<0x118>(x);   // row_shr:8
    x = dpp_add<0x142>(x);   // row_bcast:15
    x = dpp_add<0x143>(x);   // row_bcast:31
    return __int_as_float(__builtin_amdgcn_readlane(__float_as_int(x), 63));
}

// ---------------------------------------------------------------------------
// k_pre: blocks 0..1562 -> proj = node_raw @ W_feat + b_feat, skill
//        last block     -> hb = ln_b@W_gcn, wm[11], Mg[11][11],
//                          PGm[12][64] = [P @ (ln_g*W_gcn); colsum(ln_g*W_gcn)]
// ---------------------------------------------------------------------------
__global__ __launch_bounds__(256) void k_pre(
    const float* __restrict__ node_raw, const float* __restrict__ W_feat,
    const float* __restrict__ b_feat, const float* __restrict__ W_gcn,
    const float* __restrict__ ln_g, const float* __restrict__ ln_b,
    const float* __restrict__ W_edge, const float* __restrict__ b_edge,
    const float* __restrict__ W_time, const float* __restrict__ b_time,
    const float* __restrict__ W_struct, const float* __restrict__ b_struct,
    float* __restrict__ proj, int* __restrict__ skill,
    float* __restrict__ hb, float* __restrict__ wmg, float* __restrict__ Mg,
    float* __restrict__ PGm)
{
    __shared__ float red[4][64];
    __shared__ float Ws[128 * 64];          // 32 KiB staged W_feat
    int blk = blockIdx.x;
    int t = threadIdx.x;
    int dj = t & 63;

    if (blk == gridDim.x - 1) {             // params block
        int g = t >> 6;                     // dk quarter
        float acc = 0.f;
        #pragma unroll
        for (int i = 0; i < 16; ++i) {
            int dk = g * 16 + i;
            float wv = W_gcn[dk * 64 + dj];
            acc += ln_b[dk] * wv;
        }
        red[g][dj] = acc;

        if (t < 64) {
            int d = t;
            // column means + centered Gram for LN-stat precompute
            float col[11];
            col[0] = W_edge[d];
            col[1] = W_struct[d];
            #pragma unroll
            for (int i = 0; i < 8; ++i) col[2 + i] = W_time[i * 64 + d];
            col[10] = b_edge[d] + b_time[d] + 2.f * b_struct[d];
            float wmv[11];
            #pragma unroll
            for (int j = 0; j < 11; ++j) wmv[j] = wave_sum64(col[j]) * (1.f / 64.f);
            float cc[11];
            #pragma unroll
            for (int j = 0; j < 11; ++j) cc[j] = col[j] - wmv[j];
            #pragma unroll
            for (int j = 0; j < 11; ++j) {
                #pragma unroll
                for (int k = j; k < 11; ++k) {
                    float m = wave_sum64(cc[j] * cc[k]);
                    if (t == 0) { Mg[j * 11 + k] = m; Mg[k * 11 + j] = m; }
                }
            }
            if (t == 0) {
                #pragma unroll
                for (int j = 0; j < 11; ++j) wmg[j] = wmv[j];
            }

            // PGm rows 0..10 = P @ Gg, row 11 = colsum(Gg);  Gg = diag(ln_g)@W_gcn
            int j = t;   // output col
            float accp[12];
            #pragma unroll
            for (int m = 0; m < 12; ++m) accp[m] = 0.f;
            for (int d2 = 0; d2 < 64; ++d2) {
                float gg = ln_g[d2] * W_gcn[d2 * 64 + j];
                float bias_d = b_edge[d2] + b_time[d2] + 2.f * b_struct[d2];
                accp[0] = fmaf(W_edge[d2], gg, accp[0]);
                accp[1] = fmaf(W_struct[d2], gg, accp[1]);
                #pragma unroll
                for (int i = 0; i < 8; ++i)
                    accp[2 + i] = fmaf(W_time[i * 64 + d2], gg, accp[2 + i]);
                accp[10] = fmaf(bias_d, gg, accp[10]);
                accp[11] += gg;
            }
            #pragma unroll
            for (int m = 0; m < 12; ++m) PGm[m * 64 + j] = accp[m];
        }
        __syncthreads();
        if (g == 0) hb[dj] = red[0][dj] + red[1][dj] + red[2][dj] + red[3][dj];
        return;
    }

    // stage W_feat (128x64 f32 = 8192 elems): 32 coalesced rounds
    #pragma unroll
    for (int i = 0; i < 32; ++i) Ws[t + i * 256] = W_feat[t + i * 256];
    __syncthreads();

    int rg = t >> 6;
    int r0 = blk * 32 + rg * 8;
    float acc[8];
    #pragma unroll
    for (int r = 0; r < 8; ++r) acc[r] = 0.f;

    for (int k = 0; k < 128; k += 4) {
        float w0 = Ws[(k + 0) * 64 + dj];
        float w1 = Ws[(k + 1) * 64 + dj];
        float w2 = Ws[(k + 2) * 64 + dj];
        float w3 = Ws[(k + 3) * 64 + dj];
        #pragma unroll
        for (int r = 0; r < 8; ++r) {
            int row = r0 + r;
            int rc = row < NUM_NODES ? row : (NUM_NODES - 1);
            f32x4 rv = *(const f32x4*)(node_raw + (size_t)rc * 128 + k);
            acc[r] += rv.x * w0 + rv.y * w1 + rv.z * w2 + rv.w * w3;
        }
    }
    float bfv = b_feat[dj];
    #pragma unroll
    for (int r = 0; r < 8; ++r) {
        int row = r0 + r;
        if (row < NUM_NODES) proj[(size_t)row * 64 + dj] = acc[r] + bfv;
    }
    if (t < 32) {
        int row = blk * 32 + t;
        if (row < NUM_NODES) skill[row] = (int)node_raw[(size_t)row * 128];
    }
}

// ---------------------------------------------------------------------------
// k_pg: projG = proj @ (diag(ln_g) @ W_gcn)   [50000 x 64]
// ---------------------------------------------------------------------------
__global__ __launch_bounds__(256) void k_pg(
    const float* __restrict__ proj, const float* __restrict__ W_gcn,
    const float* __restrict__ ln_g, float* __restrict__ projG)
{
    __shared__ float GgS[64 * 64];          // 16 KiB
    int t = threadIdx.x, dj = t & 63;
    #pragma unroll
    for (int i = 0; i < 16; ++i) {
        int e = t + i * 256;
        GgS[e] = ln_g[e >> 6] * W_gcn[e];
    }
    __syncthreads();

    int rg = t >> 6;
    int r0 = blockIdx.x * 32 + rg * 8;
    float acc[8];
    #pragma unroll
    for (int r = 0; r < 8; ++r) acc[r] = 0.f;

    for (int k = 0; k < 64; k += 4) {
        float w0 = GgS[(k + 0) * 64 + dj];
        float w1 = GgS[(k + 1) * 64 + dj];
        float w2 = GgS[(k + 2) * 64 + dj];
        float w3 = GgS[(k + 3) * 64 + dj];
        #pragma unroll
        for (int r = 0; r < 8; ++r) {
            int row = r0 + r;
            int rc = row < NUM_NODES ? row : (NUM_NODES - 1);
            f32x4 rv = *(const f32x4*)(proj + (size_t)rc * 64 + k);
            acc[r] += rv.x * w0 + rv.y * w1 + rv.z * w2 + rv.w * w3;
        }
    }
    #pragma unroll
    for (int r = 0; r < 8; ++r) {
        int row = r0 + r;
        if (row < NUM_NODES) projG[(size_t)row * 64 + dj] = acc[r];
    }
}

// ---------------------------------------------------------------------------
// k_stat: per-node LN stats. stats[node][16] = { pm, pc2, pcw[0..10], pad }
// ---------------------------------------------------------------------------
__global__ __launch_bounds__(256) void k_stat(
    const float* __restrict__ proj,
    const float* __restrict__ W_edge, const float* __restrict__ b_edge,
    const float* __restrict__ W_time, const float* __restrict__ b_time,
    const float* __restrict__ W_struct, const float* __restrict__ b_struct,
    const float* __restrict__ wmg, float* __restrict__ stats)
{
    __shared__ float T[256][65];
    __shared__ float Wc[64][12];
    int t = threadIdx.x;
    int base = blockIdx.x * 256;

    if (t < 64) {
        int d = t;
        Wc[d][0] = W_edge[d];
        Wc[d][1] = W_struct[d];
        #pragma unroll
        for (int i = 0; i < 8; ++i) Wc[d][2 + i] = W_time[i * 64 + d];
        Wc[d][10] = b_edge[d] + b_time[d] + 2.f * b_struct[d];
        Wc[d][11] = 0.f;
    }

    int w = t >> 6, lane = t & 63;
    #pragma unroll 4
    for (int it = 0; it < 64; ++it) {
        int row = it * 4 + w;
        int node = base + row;
        int rc = node < NUM_NODES ? node : (NUM_NODES - 1);
        T[row][lane] = proj[(size_t)rc * 64 + lane];
    }
    __syncthreads();

    float sp = 0.f, spp = 0.f;
    float pw[11];
    #pragma unroll
    for (int j = 0; j < 11; ++j) pw[j] = 0.f;

    for (int d = 0; d < 64; ++d) {
        float p = T[t][d];
        f32x4 c0 = *(const f32x4*)&Wc[d][0];
        f32x4 c1 = *(const f32x4*)&Wc[d][4];
        f32x4 c2 = *(const f32x4*)&Wc[d][8];
        sp += p;
        spp = fmaf(p, p, spp);
        pw[0] = fmaf(p, c0.x, pw[0]);
        pw[1] = fmaf(p, c0.y, pw[1]);
        pw[2] = fmaf(p, c0.z, pw[2]);
        pw[3] = fmaf(p, c0.w, pw[3]);
        pw[4] = fmaf(p, c1.x, pw[4]);
        pw[5] = fmaf(p, c1.y, pw[5]);
        pw[6] = fmaf(p, c1.z, pw[6]);
        pw[7] = fmaf(p, c1.w, pw[7]);
        pw[8] = fmaf(p, c2.x, pw[8]);
        pw[9] = fmaf(p, c2.y, pw[9]);
        pw[10] = fmaf(p, c2.z, pw[10]);
    }

    int node = base + t;
    if (node < NUM_NODES) {
        float o[16];
        o[0] = sp * (1.f / 64.f);
        o[1] = spp - sp * sp * (1.f / 64.f);
        #pragma unroll
        for (int j = 0; j < 11; ++j) o[2 + j] = pw[j] - sp * wmg[j];
        o[13] = 0.f; o[14] = 0.f; o[15] = 0.f;
        float* dst = stats + (size_t)node * 16;
        #pragma unroll
        for (int q = 0; q < 4; ++q) *(f32x4*)(dst + q * 4) = *(f32x4*)&o[q * 4];
    }
}

// ---------------------------------------------------------------------------
// k_main: ONE WAVE PER SAMPLE (4 samples/block), lane = output dim.
//   Zero LDS, zero barriers, zero MFMA. Per-neighbor scalars staged in lanes,
//   broadcast via v_readlane; chain GCN is a register recurrence.
// ---------------------------------------------------------------------------
__global__ __launch_bounds__(256) void k_main(
    const int* __restrict__ ids, const int* __restrict__ eids,
    const float* __restrict__ times, const int* __restrict__ dst_ids,
    const float* __restrict__ edge_raw,
    const float* __restrict__ w_tenc, const float* __restrict__ b_tenc,
    const float* __restrict__ b_gcn, const float* __restrict__ W_out,
    const float* __restrict__ b_out,
    const float* __restrict__ proj, const float* __restrict__ projG,
    const int* __restrict__ skill,
    const float* __restrict__ hb, const float* __restrict__ wmg,
    const float* __restrict__ Mg, const float* __restrict__ PGm,
    const float* __restrict__ stats,
    float* __restrict__ out)
{
    int t = threadIdx.x;
    int lane = t & 63, w = t >> 6;
    int b = blockIdx.x * 4 + w;

    int dstb = dst_ids[b];
    int skdst = skill[dstb];

    float Mreg[12];
    #pragma unroll
    for (int j = 0; j < 12; ++j) Mreg[j] = PGm[j * 64 + lane];
    float hbv = hb[lane], bgc = b_gcn[lane], bout = b_out[lane];

    // ---- staging: lane l owns neighbors l and 64+l ----
    int l = lane;
    int base = b * N_;
    int id0 = ids[base + l];
    float tm0 = times[base + l];
    int ei0 = eids[base + l];
    bool m1 = l < 36;
    int off1 = base + 64 + (m1 ? l : 0);
    int id1r = ids[off1];
    float tm1 = times[off1];
    int ei1 = eids[off1];
    int id1 = m1 ? id1r : 0;

    unsigned long long bal0 = __ballot(id0 > 0);
    unsigned long long bal1 = __ballot(m1 && (id1r > 0));
    int v = __popcll(bal0) + __popcll(bal1);

    float e0 = edge_raw[(size_t)ei0 * 128];
    float e1 = edge_raw[(size_t)(m1 ? ei1 : ei0) * 128];
    int sk0 = skill[id0];
    int sk1 = skill[id1];
    float pd = proj[(size_t)dstb * 64 + lane];   // dst proj row (for dst_emb)

    float V0[12], V1[12], r0s, r1s;
    {   // neighbor batch 0
        float u[11];
        u[0] = e0;
        u[1] = (id0 == dstb ? 1.f : 0.f) + (sk0 == skdst ? 1.f : 0.f);
        #pragma unroll
        for (int i = 0; i < 8; ++i) u[2 + i] = __cosf(fmaf(tm0, w_tenc[i], b_tenc[i]));
        u[10] = 1.f;
        const f32x4* sp = (const f32x4*)(stats + (size_t)id0 * 16);
        f32x4 s0 = sp[0], s1 = sp[1], s2 = sp[2], s3 = sp[3];
        float pw[11] = {s0.z, s0.w, s1.x, s1.y, s1.z, s1.w,
                        s2.x, s2.y, s2.z, s2.w, s3.x};
        float mu = s0.x, q = s0.y;
        #pragma unroll
        for (int j = 0; j < 11; ++j) { mu = fmaf(u[j], wmg[j], mu); q = fmaf(2.f * u[j], pw[j], q); }
        #pragma unroll
        for (int j = 0; j < 11; ++j) {
            float tj = 0.f;
            #pragma unroll
            for (int k = 0; k < 11; ++k) tj = fmaf(Mg[j * 11 + k], u[k], tj);
            q = fmaf(u[j], tj, q);
        }
        float rstd = rsqrtf(fmaxf(q, 0.f) * (1.f / 64.f) + 1e-5f);
        #pragma unroll
        for (int j = 0; j < 11; ++j) V0[j] = rstd * u[j];
        V0[11] = -rstd * mu;
        r0s = rstd;
    }
    {   // neighbor batch 1
        float u[11];
        u[0] = e1;
        u[1] = (id1 == dstb ? 1.f : 0.f) + (sk1 == skdst ? 1.f : 0.f);
        #pragma unroll
        for (int i = 0; i < 8; ++i) u[2 + i] = __cosf(fmaf(tm1, w_tenc[i], b_tenc[i]));
        u[10] = 1.f;
        const f32x4* sp = (const f32x4*)(stats + (size_t)id1 * 16);
        f32x4 s0 = sp[0], s1 = sp[1], s2 = sp[2], s3 = sp[3];
        float pw[11] = {s0.z, s0.w, s1.x, s1.y, s1.z, s1.w,
                        s2.x, s2.y, s2.z, s2.w, s3.x};
        float mu = s0.x, q = s0.y;
        #pragma unroll
        for (int j = 0; j < 11; ++j) { mu = fmaf(u[j], wmg[j], mu); q = fmaf(2.f * u[j], pw[j], q); }
        #pragma unroll
        for (int j = 0; j < 11; ++j) {
            float tj = 0.f;
            #pragma unroll
            for (int k = 0; k < 11; ++k) tj = fmaf(Mg[j * 11 + k], u[k], tj);
            q = fmaf(u[j], tj, q);
        }
        float rstd = rsqrtf(fmaxf(q, 0.f) * (1.f / 64.f) + 1e-5f);
        #pragma unroll
        for (int j = 0; j < 11; ++j) V1[j] = rstd * u[j];
        V1[11] = -rstd * mu;
        r1s = rstd;
    }

    // ---- main loop: h[n] = rstd_n*projG[id_n][lane] + V_n@Mreg + hbv ----
    float po = 0.f, hprev = 0.f;
    float pg[8], pgn[8];
    #pragma unroll
    for (int j = 0; j < 8; ++j) {
        int sid = __builtin_amdgcn_readlane(id0, j);
        pg[j] = projG[(size_t)sid * 64 + lane];
    }
    for (int g = 0; g < 8; ++g) {                 // n = 0..63
        if (g < 7) {
            #pragma unroll
            for (int j = 0; j < 8; ++j) {
                int sid = __builtin_amdgcn_readlane(id0, g * 8 + 8 + j);
                pgn[j] = projG[(size_t)sid * 64 + lane];
            }
        } else {
            #pragma unroll
            for (int j = 0; j < 8; ++j) {
                int sid = __builtin_amdgcn_readlane(id1, j);
                pgn[j] = projG[(size_t)sid * 64 + lane];
            }
        }
        #pragma unroll
        for (int j = 0; j < 8; ++j) {
            int n = g * 8 + j;
            float h = fmaf(rlf(r0s, n), pg[j], hbv);
            #pragma unroll
            for (int q2 = 0; q2 < 12; ++q2) h = fmaf(rlf(V0[q2], n), Mreg[q2], h);
            bool hin = (n >= 1) && (n < v);
            float a_ = hin ? 0.5f : 1.f;
            float dp = (n >= 2 && n <= v) ? 0.70710678118f : 1.f;
            float coef = hin ? dp * 0.70710678118f : 0.f;
            float o = fmaf(h, a_, fmaf(coef, hprev, bgc));
            po += fmaxf(o, 0.f);
            hprev = h;
        }
        #pragma unroll
        for (int j = 0; j < 8; ++j) pg[j] = pgn[j];
    }
    for (int g = 0; g < 4; ++g) {                 // n = 64..95
        #pragma unroll
        for (int j = 0; j < 8; ++j) {
            int nn = g * 8 + 8 + j;
            int sid = __builtin_amdgcn_readlane(id1, nn < 36 ? nn : 0);
            pgn[j] = projG[(size_t)sid * 64 + lane];
        }
        #pragma unroll
        for (int j = 0; j < 8; ++j) {
            int nl = g * 8 + j;
            int n = 64 + nl;
            float h = fmaf(rlf(r1s, nl), pg[j], hbv);
            #pragma unroll
            for (int q2 = 0; q2 < 12; ++q2) h = fmaf(rlf(V1[q2], nl), Mreg[q2], h);
            bool hin = (n >= 1) && (n < v);
            float a_ = hin ? 0.5f : 1.f;
            float dp = (n >= 2 && n <= v) ? 0.70710678118f : 1.f;
            float coef = hin ? dp * 0.70710678118f : 0.f;
            float o = fmaf(h, a_, fmaf(coef, hprev, bgc));
            po += fmaxf(o, 0.f);
            hprev = h;
        }
        #pragma unroll
        for (int j = 0; j < 8; ++j) pg[j] = pgn[j];
    }
    #pragma unroll
    for (int j = 0; j < 4; ++j) {                 // n = 96..99
        int nl = 32 + j;
        int n = 96 + j;
        float h = fmaf(rlf(r1s, nl), pg[j], hbv);
        #pragma unroll
        for (int q2 = 0; q2 < 12; ++q2) h = fmaf(rlf(V1[q2], nl), Mreg[q2], h);
        bool hin = (n >= 1) && (n < v);
        float a_ = hin ? 0.5f : 1.f;
        float dp = (n >= 2 && n <= v) ? 0.70710678118f : 1.f;
        float coef = hin ? dp * 0.70710678118f : 0.f;
        float o = fmaf(h, a_, fmaf(coef, hprev, bgc));
        po += fmaxf(o, 0.f);
        hprev = h;
    }

    // ---- epilogue: two matvecs with W_out via readlane broadcast ----
    float poo = po * (1.f / (float)N_);
    float osrc = bout, odst = bout;
    #pragma unroll 8
    for (int dk = 0; dk < 64; ++dk) {
        float wv = W_out[dk * 64 + lane];
        osrc = fmaf(rlf(poo, dk), wv, osrc);
        odst = fmaf(rlf(pd, dk), wv, odst);
    }
    out[(size_t)b * 64 + lane] = osrc;
    out[(size_t)(B_ + b) * 64 + lane] = odst;
}

// ---------------------------------------------------------------------------
extern "C" void kernel_launch(void* const* d_in, const int* in_sizes, int n_in,
                              void* d_out, int out_size, void* d_ws, size_t ws_size,
                              hipStream_t stream)
{
    const int*   ids      = (const int*)d_in[0];
    const int*   eids     = (const int*)d_in[1];
    const float* times    = (const float*)d_in[2];
    const int*   dst_ids  = (const int*)d_in[3];
    const float* node_raw = (const float*)d_in[4];
    const float* edge_raw = (const float*)d_in[5];
    const float* W_feat   = (const float*)d_in[6];
    const float* b_feat   = (const float*)d_in[7];
    const float* W_edge   = (const float*)d_in[8];
    const float* b_edge   = (const float*)d_in[9];
    const float* W_time   = (const float*)d_in[10];
    const float* b_time   = (const float*)d_in[11];
    const float* W_struct = (const float*)d_in[12];
    const float* b_struct = (const float*)d_in[13];
    const float* w_tenc   = (const float*)d_in[14];
    const float* b_tenc   = (const float*)d_in[15];
    const float* ln_g     = (const float*)d_in[16];
    const float* ln_b     = (const float*)d_in[17];
    const float* W_gcn    = (const float*)d_in[18];
    const float* b_gcn    = (const float*)d_in[19];
    const float* W_out    = (const float*)d_in[20];
    const float* b_out    = (const float*)d_in[21];

    char* ws = (char*)d_ws;
    float* proj   = (float*)ws;                          // 12,800,000 B
    int*   skill  = (int*)(ws + 12800000);               //    200,000 B
    float* hb     = (float*)(ws + 13008192);             //        256 B
    float* wmg    = (float*)(ws + 13008448);             //         64 B
    float* Mg     = (float*)(ws + 13008512);             //        512 B
    float* PGm    = (float*)(ws + 13009024);             //      3,072 B
    float* stats  = (float*)(ws + 13100032);             //  3,200,000 B
    float* projG  = (float*)(ws + 16400000);             // 12,800,000 B

    k_pre<<<1564, 256, 0, stream>>>(node_raw, W_feat, b_feat, W_gcn, ln_g, ln_b,
                                    W_edge, b_edge, W_time, b_time, W_struct, b_struct,
                                    proj, skill, hb, wmg, Mg, PGm);
    k_pg<<<1563, 256, 0, stream>>>(proj, W_gcn, ln_g, projG);
    k_stat<<<196, 256, 0, stream>>>(proj, W_edge, b_edge, W_time, b_time,
                                    W_struct, b_struct, wmg, stats);
    k_main<<<1024, 256, 0, stream>>>(ids, eids, times, dst_ids, edge_raw,
                                     w_tenc, b_tenc, b_gcn, W_out, b_out,
                                     proj, projG, skill, hb, wmg, Mg, PGm, stats,
                                     (float*)d_out);
}